// Round 9
// baseline (523.116 us; speedup 1.0000x reference)
//
#include <hip/hip_runtime.h>

#define N_USERS 100000
#define N_ITEMS 50000
#define N_NODES 150000
#define EMBED   64
#define NNZV    4000000
#define BATCH   4096
// bucket = row / 293 : 293 rows per bucket, EXACTLY 512 buckets = 2 blocks/CU
// for partb (R8 validated the no-tail principle at 256; 512 doubles resident
// waves for the latency-bound scatter). parta likewise re-gridded to 512
// blocks (was 245 < 256 CUs -> 25% occupancy; the ledger says parta ~165us is
// the #3 cost and it's latency-bound).
#define BKW     293
#define NBKT    512
// staging capacity per bucket: mean 7812.5, binomial sd 88.3 -> +15 sigma
#define CAP     9152
// edges per parta block: 512 blocks exactly
#define EPB     7813

// ---------------- Phase A: partition edges into 293-row buckets --------------
// Proven R0/R6 mechanics (LDS bucket count + rank scatter). NO returning
// global atomics on the edge path (R7: +250MB fabric traffic, 3x slower).
// Plain (non-nt) staging stores: scattered 8B writes need L2 write-merge (R11).
// Record: low32 = rl<<18 | col (rl<293 -> 9 bits, col<150000 -> 18 bits),
// high32 = val bits.
__global__ __launch_bounds__(512) void k_parta(
        const int* __restrict__ row, const int* __restrict__ col,
        const float* __restrict__ vals, int* __restrict__ bcnt,
        unsigned long long* __restrict__ staging, int nnz) {
    __shared__ int cnt[NBKT];
    __shared__ int base_s[NBKT];
    int tid = threadIdx.x;
    cnt[tid] = 0;
    __syncthreads();
    int tile0 = blockIdx.x * EPB;
    int e_end = tile0 + EPB; if (e_end > nnz) e_end = nnz;
    for (int k = 0; k < 16; k++) {
        int e = tile0 + k * 512 + tid;
        if (e < e_end) atomicAdd(&cnt[row[e] / BKW], 1);
    }
    __syncthreads();
    {
        int c_ = cnt[tid];
        base_s[tid] = c_ ? (tid * CAP + atomicAdd(&bcnt[tid], c_)) : 0;
        cnt[tid] = 0;                                   // reuse as rank counter
    }
    __syncthreads();
    for (int k = 0; k < 16; k++) {
        int e = tile0 + k * 512 + tid;
        if (e < e_end) {
            int r = row[e];
            int b = r / BKW;
            int rank = atomicAdd(&cnt[b], 1);
            unsigned int key = ((unsigned int)(r - b * BKW) << 18) | (unsigned int)col[e];
            unsigned long long rec = (unsigned long long)key
                                   | ((unsigned long long)__float_as_uint(vals[e]) << 32);
            staging[base_s[b] + rank] = rec;
        }
    }
}

// ------- Phase B: bucket scan + per-bucket histogram/scan + local scatter ----
// One block per bucket, 512 blocks = 2/CU (no tail). 293 rows, 1 per thread.
__global__ __launch_bounds__(512) void k_partb(
        const int* __restrict__ bcnt,
        const unsigned long long* __restrict__ staging,
        int* __restrict__ row_ptr,
        unsigned long long* __restrict__ edges) {
    __shared__ int s[512];
    __shared__ int cnt[BKW];
    __shared__ int cur[BKW];
    __shared__ int base_sh;
    int b = blockIdx.x;
    int t = threadIdx.x;

    // exclusive prefix of the 512 bucket counts at position b
    int v = bcnt[t];
    s[t] = v;
    __syncthreads();
    for (int off = 1; off < 512; off <<= 1) {
        int u = (t >= off) ? s[t - off] : 0;
        __syncthreads();
        s[t] += u;
        __syncthreads();
    }
    if (t == b) base_sh = s[t] - v;
    if (b == 0 && t == 0) row_ptr[N_NODES] = NNZV;
    __syncthreads();
    int base = base_sh;
    int n    = bcnt[b];
    const unsigned long long* sb = staging + (size_t)b * CAP;

    // per-bucket row histogram (293 rows, 1 per thread)
    if (t < BKW) cnt[t] = 0;
    __syncthreads();
    for (int i = t; i < n; i += 512)
        atomicAdd(&cnt[(unsigned int)sb[i] >> 18], 1);
    __syncthreads();
    int c = (t < BKW) ? cnt[t] : 0;
    s[t] = c;
    __syncthreads();
    for (int off = 1; off < 512; off <<= 1) {
        int u = (t >= off) ? s[t - off] : 0;
        __syncthreads();
        s[t] += u;
        __syncthreads();
    }
    int excl = s[t] - c;
    if (t < BKW) cur[t] = excl;
    int r = b * BKW + t;
    if (t < BKW && r < N_NODES) row_ptr[r] = base + excl;
    __syncthreads();
    // rank scatter into dense CSR
    for (int i = t; i < n; i += 512) {
        unsigned long long rec = sb[i];
        unsigned int key = (unsigned int)rec;
        int rank = atomicAdd(&cur[key >> 18], 1);
        edges[base + rank] = (rec & 0xFFFFFFFF00000000ull) | (key & 0x3FFFFu);
    }
}

// ---------------- single-row SpMM helper (R0-proven, used by batch kernel) ---
__device__ __forceinline__ float4 spmm_row(const int* row_ptr,
                                           const unsigned long long* edges,
                                           const float4* __restrict__ eu4,
                                           const float4* __restrict__ ei4s,
                                           int r, int lane) {
    int g = lane >> 4;
    int d = lane & 15;
    int start = row_ptr[r];
    int end   = row_ptr[r + 1];
    float4 acc = make_float4(0.f, 0.f, 0.f, 0.f);
    for (int e0 = start; e0 < end; e0 += 64) {
        int ei = e0 + lane;
        unsigned long long rec = 0ull;
        if (ei < end) rec = __builtin_nontemporal_load(edges + ei);
        int clo = (int)(rec & 0xffffffffull);
        int vhi = (int)(rec >> 32);
        int nleft = end - e0;
        int kmax = (nleft + 3) >> 2;          // uniform across the wave
        #pragma unroll 4
        for (int k = 0; k < kmax; k++) {
            int src = 4 * k + g;
            int cc = __shfl(clo, src);
            float vv = __int_as_float(__shfl(vhi, src));
            const float4* basep = (cc < N_USERS) ? eu4 : ei4s;
            float4 e = basep[cc * 16 + d];
            acc.x += vv * e.x;
            acc.y += vv * e.y;
            acc.z += vv * e.z;
            acc.w += vv * e.w;
        }
    }
    acc.x += __shfl_xor(acc.x, 16);
    acc.y += __shfl_xor(acc.y, 16);
    acc.z += __shfl_xor(acc.z, 16);
    acc.w += __shfl_xor(acc.w, 16);
    acc.x += __shfl_xor(acc.x, 32);
    acc.y += __shfl_xor(acc.y, 32);
    acc.z += __shfl_xor(acc.z, 32);
    acc.w += __shfl_xor(acc.w, 32);
    return acc;
}

// ---------------- 4-row-per-wave SpMM (layers 1 & 2) -------------------------
// R0 vs R6 A/B: this kernel sits at the ~3.6 TB/s L2-fill throughput wall for
// random gathers (4x ILP -> zero delta). Kept as-is.
__global__ void k_spmm4(const int* __restrict__ row_ptr,
                        const unsigned long long* __restrict__ edges,
                        const float4* __restrict__ eu4,
                        const float4* __restrict__ ei4s,
                        float4* __restrict__ Eout) {
    int lane = threadIdx.x & 63;
    int wv   = threadIdx.x >> 6;
    int rbase = (blockIdx.x * 4 + wv) * 4;       // 4 rows per wave
    if (rbase >= N_NODES) return;
    int g = lane >> 4;
    int d = lane & 15;
    int st[4], en[4], len[4];
    #pragma unroll
    for (int i = 0; i < 4; i++) {
        int r = rbase + i;
        if (r < N_NODES) { st[i] = row_ptr[r]; en[i] = row_ptr[r + 1]; }
        else             { st[i] = 0;          en[i] = 0; }
        len[i] = en[i] - st[i];
    }
    int maxlen = len[0];
    #pragma unroll
    for (int i = 1; i < 4; i++) maxlen = (len[i] > maxlen) ? len[i] : maxlen;

    float4 acc[4];
    #pragma unroll
    for (int i = 0; i < 4; i++) acc[i] = make_float4(0.f, 0.f, 0.f, 0.f);

    for (int off = 0; off < maxlen; off += 64) {
        int clo[4], vhi[4], kmax[4];
        #pragma unroll
        for (int i = 0; i < 4; i++) {
            int ei = st[i] + off + lane;
            unsigned long long rec = 0ull;
            if (ei < en[i]) rec = __builtin_nontemporal_load(edges + ei);
            clo[i] = (int)(rec & 0xffffffffull);
            vhi[i] = (int)(rec >> 32);
            int nleft = len[i] - off;
            if (nleft < 0) nleft = 0; else if (nleft > 64) nleft = 64;
            kmax[i] = (nleft + 3) >> 2;          // wave-uniform per row
        }
        int kmx = (maxlen - off + 3) >> 2; if (kmx > 16) kmx = 16;
        #pragma unroll 4
        for (int k = 0; k < kmx; k++) {
            int src = 4 * k + g;
            #pragma unroll
            for (int i = 0; i < 4; i++) {
                if (k < kmax[i]) {               // wave-uniform branch
                    int cc = __shfl(clo[i], src);
                    float vv = __int_as_float(__shfl(vhi[i], src));
                    const float4* bp = (cc < N_USERS) ? eu4 : ei4s;
                    float4 e = bp[cc * 16 + d];
                    acc[i].x += vv * e.x;
                    acc[i].y += vv * e.y;
                    acc[i].z += vv * e.z;
                    acc[i].w += vv * e.w;
                }
            }
        }
    }
    #pragma unroll
    for (int i = 0; i < 4; i++) {
        acc[i].x += __shfl_xor(acc[i].x, 16);
        acc[i].y += __shfl_xor(acc[i].y, 16);
        acc[i].z += __shfl_xor(acc[i].z, 16);
        acc[i].w += __shfl_xor(acc[i].w, 16);
        acc[i].x += __shfl_xor(acc[i].x, 32);
        acc[i].y += __shfl_xor(acc[i].y, 32);
        acc[i].z += __shfl_xor(acc[i].z, 32);
        acc[i].w += __shfl_xor(acc[i].w, 32);
    }
    if (lane < 16) {
        #pragma unroll
        for (int i = 0; i < 4; i++)
            if (rbase + i < N_NODES) Eout[(rbase + i) * 16 + lane] = acc[i];
    }
}

// --------- layer-3 SpMM restricted to batch rows, fused epilogue -------------
__global__ void k_spmm_batch(const int* __restrict__ row_ptr,
                             const unsigned long long* __restrict__ edges,
                             const float4* __restrict__ Ein,   // E2
                             const int* __restrict__ bu, const int* __restrict__ bp,
                             const int* __restrict__ bn,
                             float4* __restrict__ out) {
    int lane = threadIdx.x & 63;
    int j = blockIdx.x * 4 + (threadIdx.x >> 6);
    if (j >= 3 * BATCH) return;
    int r;
    if (j < BATCH)          r = bu[j];
    else if (j < 2 * BATCH) r = N_USERS + bp[j - BATCH];
    else                    r = N_USERS + bn[j - 2 * BATCH];
    float4 acc = spmm_row(row_ptr, edges, Ein, Ein, r, lane);
    if (lane < 16) {
        float4 e2 = Ein[r * 16 + lane];
        float4 o  = out[j * 16 + lane];
        o.x += 0.25f * (acc.x + e2.x);
        o.y += 0.25f * (acc.y + e2.y);
        o.z += 0.25f * (acc.z + e2.z);
        o.w += 0.25f * (acc.w + e2.w);
        out[j * 16 + lane] = o;
    }
}

// ------ fused gather: out = 0.25*(E0[batch] + E1[batch]) (one dispatch) ------
__global__ void k_gather2(const int* __restrict__ bu, const int* __restrict__ bp,
                          const int* __restrict__ bn,
                          const float4* __restrict__ eu4,
                          const float4* __restrict__ ei4s,
                          const float4* __restrict__ E1,
                          float4* __restrict__ out) {
    int idx = blockIdx.x * blockDim.x + threadIdx.x;
    if (idx >= 3 * BATCH * 16) return;
    int j = idx >> 4;
    int d = idx & 15;
    int node;
    if (j < BATCH)          node = bu[j];
    else if (j < 2 * BATCH) node = N_USERS + bp[j - BATCH];
    else                    node = N_USERS + bn[j - 2 * BATCH];
    const float4* basep = (node < N_USERS) ? eu4 : ei4s;
    float4 v0 = basep[node * 16 + d];
    float4 v1 = E1[node * 16 + d];
    float4 o;
    o.x = 0.25f * (v0.x + v1.x);
    o.y = 0.25f * (v0.y + v1.y);
    o.z = 0.25f * (v0.z + v1.z);
    o.w = 0.25f * (v0.w + v1.w);
    out[idx] = o;
}

extern "C" void kernel_launch(void* const* d_in, const int* in_sizes, int n_in,
                              void* d_out, int out_size, void* d_ws, size_t ws_size,
                              hipStream_t stream) {
    const int*   bu   = (const int*)d_in[0];
    const int*   bp   = (const int*)d_in[1];
    const int*   bn   = (const int*)d_in[2];
    const float* eu   = (const float*)d_in[3];
    const float* ei   = (const float*)d_in[4];
    const int*   row  = (const int*)d_in[5];
    const int*   col  = (const int*)d_in[6];
    const float* vals = (const float*)d_in[7];
    float* out = (float*)d_out;

    char* p = (char*)d_ws;
    auto alloc = [&](size_t nbytes) {
        void* r = (void*)p;
        p += (nbytes + 255) & ~(size_t)255;
        return r;
    };
    float*              E_a     = (float*)alloc((size_t)N_NODES * EMBED * 4);  // 38.4 MB
    float*              E_b     = (float*)alloc((size_t)N_NODES * EMBED * 4);  // 38.4 MB
    unsigned long long* edges   = (unsigned long long*)alloc((size_t)NNZV * 8);// 32.0 MB
    int*                row_ptr = (int*)alloc((N_NODES + 1) * 4);
    int*                bcnt    = (int*)alloc(NBKT * 4);
    (void)ws_size; (void)n_in; (void)in_sizes; (void)out_size;

    // staging (NBKT*CAP*8 = 37.5 MB) overlays E_b (38.4 MB): staging is dead
    // after k_partb, before layer-2 spmm writes E_b (same stream => ordered).
    // Footprint = the R0/R6/R8-proven ~109 MB envelope.
    unsigned long long* staging = (unsigned long long*)E_b;

    const float4* eu4  = (const float4*)eu;
    const float4* ei4s = (const float4*)ei - (size_t)N_USERS * 16;  // pre-shifted

    const int nnz = NNZV;
    hipMemsetAsync(bcnt, 0, NBKT * sizeof(int), stream);

    k_parta<<<NBKT, 512, 0, stream>>>(row, col, vals, bcnt, staging, nnz);
    k_partb<<<NBKT, 512, 0, stream>>>(bcnt, staging, row_ptr, edges);

    // layer 1: E1 = A * E0 (virtual concat input)
    k_spmm4<<<(N_NODES + 15) / 16, 256, 0, stream>>>(row_ptr, edges, eu4, ei4s,
                                                     (float4*)E_a);
    // out = 0.25*(E0[batch] + E1[batch])  (fused init+acc, one dispatch)
    k_gather2<<<(3 * BATCH * 16 + 255) / 256, 256, 0, stream>>>(
        bu, bp, bn, eu4, ei4s, (const float4*)E_a, (float4*)out);

    // layer 2: E2 = A * E1 (global node ids -> same base twice, no shift)
    k_spmm4<<<(N_NODES + 15) / 16, 256, 0, stream>>>(row_ptr, edges,
                                                     (const float4*)E_a,
                                                     (const float4*)E_a,
                                                     (float4*)E_b);

    // layer 3: only batch rows, fused  out += 0.25*E2[batch] + 0.25*E3[batch]
    k_spmm_batch<<<(3 * BATCH + 3) / 4, 256, 0, stream>>>(
        row_ptr, edges, (const float4*)E_b, bu, bp, bn, (float4*)out);
}

// Round 11
// 501.496 us; speedup vs baseline: 1.0431x; 1.0431x over previous
//
#include <hip/hip_runtime.h>

#define N_USERS 100000
#define N_ITEMS 50000
#define N_NODES 150000
#define EMBED   64
#define NNZV    4000000
#define BATCH   4096
// bucket = row / 586 : EXACTLY 256 buckets = 1 partb block/CU (R8-proven best;
// R9's 512-bucket re-grid regressed +15us -> parta/partb are LDS-atomic-PIPE
// bound, occupancy-invariant. Geometry reverted to R8.)
#define BKW     586
#define NBKT    256
// staging capacity per bucket: mean 15625, sd ~125 -> +21 sigma, 64-aligned
#define CAP     18304

// ---------------- Phase A: partition edges into 586-row buckets --------------
// R8-verbatim. NO returning global atomics (R7: +250MB fabric traffic, 3x).
// Plain (non-nt) staging stores: scattered 8B writes need L2 write-merge (R11).
// Record: low32 = rl<<18 | col (rl<586 -> 10 bits, col -> 18 bits), hi32 = val.
__global__ __launch_bounds__(512) void k_parta(
        const int* __restrict__ row, const int* __restrict__ col,
        const float* __restrict__ vals, int* __restrict__ bcnt,
        unsigned long long* __restrict__ staging, int nnz) {
    __shared__ int cnt[NBKT];
    __shared__ int base_s[NBKT];
    int tid = threadIdx.x;
    if (tid < NBKT) cnt[tid] = 0;
    __syncthreads();
    int tile0 = blockIdx.x * 16384;
    for (int k = 0; k < 32; k++) {
        int e = tile0 + k * 512 + tid;
        if (e < nnz) atomicAdd(&cnt[row[e] / BKW], 1);
    }
    __syncthreads();
    if (tid < NBKT) {
        int c_ = cnt[tid];
        base_s[tid] = c_ ? (tid * CAP + atomicAdd(&bcnt[tid], c_)) : 0;
        cnt[tid] = 0;                                   // reuse as rank counter
    }
    __syncthreads();
    for (int k = 0; k < 32; k++) {
        int e = tile0 + k * 512 + tid;
        if (e < nnz) {
            int r = row[e];
            int b = r / BKW;
            int rank = atomicAdd(&cnt[b], 1);
            unsigned int key = ((unsigned int)(r - b * BKW) << 18) | (unsigned int)col[e];
            unsigned long long rec = (unsigned long long)key
                                   | ((unsigned long long)__float_as_uint(vals[e]) << 32);
            staging[base_s[b] + rank] = rec;
        }
    }
}

// -------- tiny one-block scan of the 256 bucket counts -> bucket bases -------
// (hoisted out of partb, where all 256 blocks redid it redundantly)
__global__ __launch_bounds__(512) void k_bscan(const int* __restrict__ bcnt,
                                               int* __restrict__ bbase) {
    __shared__ int s[512];
    int t = threadIdx.x;
    int v = (t < NBKT) ? bcnt[t] : 0;
    s[t] = v;
    __syncthreads();
    for (int off = 1; off < 512; off <<= 1) {
        int u = (t >= off) ? s[t - off] : 0;
        __syncthreads();
        s[t] += u;
        __syncthreads();
    }
    if (t < NBKT) bbase[t] = s[t] - v;                  // exclusive prefix
}

// ------- Phase B: per-bucket row histogram/scan + local scatter (R8 core) ----
// One block per bucket, 256 blocks = 1/CU (no tail). 586 rows, 2 per thread.
__global__ __launch_bounds__(512) void k_partb(
        const int* __restrict__ bcnt,
        const int* __restrict__ bbase,
        const unsigned long long* __restrict__ staging,
        int* __restrict__ row_ptr,
        unsigned long long* __restrict__ edges) {
    __shared__ int s[512];
    __shared__ int cnt[BKW];
    __shared__ int cur[BKW];
    int b = blockIdx.x;
    int t = threadIdx.x;
    if (b == 0 && t == 0) row_ptr[N_NODES] = NNZV;
    int base = bbase[b];
    int n    = bcnt[b];
    const unsigned long long* sb = staging + (size_t)b * CAP;

    // per-bucket row histogram (586 rows, 2 per thread)
    int j0 = 2 * t, j1 = 2 * t + 1;
    if (j0 < BKW) cnt[j0] = 0;
    if (j1 < BKW) cnt[j1] = 0;
    __syncthreads();
    for (int i = t; i < n; i += 512)
        atomicAdd(&cnt[(unsigned int)sb[i] >> 18], 1);
    __syncthreads();
    // scan: each thread owns rows 2t, 2t+1
    int c0 = (j0 < BKW) ? cnt[j0] : 0;
    int c1 = (j1 < BKW) ? cnt[j1] : 0;
    int pair = c0 + c1;
    s[t] = pair;
    __syncthreads();
    for (int off = 1; off < 512; off <<= 1) {
        int u = (t >= off) ? s[t - off] : 0;
        __syncthreads();
        s[t] += u;
        __syncthreads();
    }
    int excl = s[t] - pair;
    if (j0 < BKW) cur[j0] = excl;
    if (j1 < BKW) cur[j1] = excl + c0;
    int r0 = b * BKW + j0;
    int r1 = b * BKW + j1;
    if (j0 < BKW && r0 < N_NODES) row_ptr[r0] = base + excl;
    if (j1 < BKW && r1 < N_NODES) row_ptr[r1] = base + excl + c0;
    __syncthreads();
    // rank scatter into dense CSR
    for (int i = t; i < n; i += 512) {
        unsigned long long rec = sb[i];
        unsigned int key = (unsigned int)rec;
        int rank = atomicAdd(&cur[key >> 18], 1);
        edges[base + rank] = (rec & 0xFFFFFFFF00000000ull) | (key & 0x3FFFFu);
    }
}

// ---------------- single-row SpMM helper (R0-proven) -------------------------
__device__ __forceinline__ float4 spmm_row(const int* row_ptr,
                                           const unsigned long long* edges,
                                           const float4* __restrict__ eu4,
                                           const float4* __restrict__ ei4s,
                                           int r, int lane) {
    int g = lane >> 4;
    int d = lane & 15;
    int start = row_ptr[r];
    int end   = row_ptr[r + 1];
    float4 acc = make_float4(0.f, 0.f, 0.f, 0.f);
    for (int e0 = start; e0 < end; e0 += 64) {
        int ei = e0 + lane;
        unsigned long long rec = 0ull;
        if (ei < end) rec = __builtin_nontemporal_load(edges + ei);
        int clo = (int)(rec & 0xffffffffull);
        int vhi = (int)(rec >> 32);
        int nleft = end - e0;
        int kmax = (nleft + 3) >> 2;          // uniform across the wave
        #pragma unroll 4
        for (int k = 0; k < kmax; k++) {
            int src = 4 * k + g;
            int cc = __shfl(clo, src);
            float vv = __int_as_float(__shfl(vhi, src));
            const float4* basep = (cc < N_USERS) ? eu4 : ei4s;
            float4 e = basep[cc * 16 + d];
            acc.x += vv * e.x;
            acc.y += vv * e.y;
            acc.z += vv * e.z;
            acc.w += vv * e.w;
        }
    }
    acc.x += __shfl_xor(acc.x, 16);
    acc.y += __shfl_xor(acc.y, 16);
    acc.z += __shfl_xor(acc.z, 16);
    acc.w += __shfl_xor(acc.w, 16);
    acc.x += __shfl_xor(acc.x, 32);
    acc.y += __shfl_xor(acc.y, 32);
    acc.z += __shfl_xor(acc.z, 32);
    acc.w += __shfl_xor(acc.w, 32);
    return acc;
}

// ---------------- 4-row-per-wave SpMM (layers 1 & 2) -------------------------
// R0 vs R6 A/B: sits at the ~3.6 TB/s random-gather throughput wall
// (4x ILP -> zero delta). Kept as-is.
__global__ void k_spmm4(const int* __restrict__ row_ptr,
                        const unsigned long long* __restrict__ edges,
                        const float4* __restrict__ eu4,
                        const float4* __restrict__ ei4s,
                        float4* __restrict__ Eout) {
    int lane = threadIdx.x & 63;
    int wv   = threadIdx.x >> 6;
    int rbase = (blockIdx.x * 4 + wv) * 4;       // 4 rows per wave
    if (rbase >= N_NODES) return;
    int g = lane >> 4;
    int d = lane & 15;
    int st[4], en[4], len[4];
    #pragma unroll
    for (int i = 0; i < 4; i++) {
        int r = rbase + i;
        if (r < N_NODES) { st[i] = row_ptr[r]; en[i] = row_ptr[r + 1]; }
        else             { st[i] = 0;          en[i] = 0; }
        len[i] = en[i] - st[i];
    }
    int maxlen = len[0];
    #pragma unroll
    for (int i = 1; i < 4; i++) maxlen = (len[i] > maxlen) ? len[i] : maxlen;

    float4 acc[4];
    #pragma unroll
    for (int i = 0; i < 4; i++) acc[i] = make_float4(0.f, 0.f, 0.f, 0.f);

    for (int off = 0; off < maxlen; off += 64) {
        int clo[4], vhi[4], kmax[4];
        #pragma unroll
        for (int i = 0; i < 4; i++) {
            int ei = st[i] + off + lane;
            unsigned long long rec = 0ull;
            if (ei < en[i]) rec = __builtin_nontemporal_load(edges + ei);
            clo[i] = (int)(rec & 0xffffffffull);
            vhi[i] = (int)(rec >> 32);
            int nleft = len[i] - off;
            if (nleft < 0) nleft = 0; else if (nleft > 64) nleft = 64;
            kmax[i] = (nleft + 3) >> 2;          // wave-uniform per row
        }
        int kmx = (maxlen - off + 3) >> 2; if (kmx > 16) kmx = 16;
        #pragma unroll 4
        for (int k = 0; k < kmx; k++) {
            int src = 4 * k + g;
            #pragma unroll
            for (int i = 0; i < 4; i++) {
                if (k < kmax[i]) {               // wave-uniform branch
                    int cc = __shfl(clo[i], src);
                    float vv = __int_as_float(__shfl(vhi[i], src));
                    const float4* bp = (cc < N_USERS) ? eu4 : ei4s;
                    float4 e = bp[cc * 16 + d];
                    acc[i].x += vv * e.x;
                    acc[i].y += vv * e.y;
                    acc[i].z += vv * e.z;
                    acc[i].w += vv * e.w;
                }
            }
        }
    }
    #pragma unroll
    for (int i = 0; i < 4; i++) {
        acc[i].x += __shfl_xor(acc[i].x, 16);
        acc[i].y += __shfl_xor(acc[i].y, 16);
        acc[i].z += __shfl_xor(acc[i].z, 16);
        acc[i].w += __shfl_xor(acc[i].w, 16);
        acc[i].x += __shfl_xor(acc[i].x, 32);
        acc[i].y += __shfl_xor(acc[i].y, 32);
        acc[i].z += __shfl_xor(acc[i].z, 32);
        acc[i].w += __shfl_xor(acc[i].w, 32);
    }
    if (lane < 16) {
        #pragma unroll
        for (int i = 0; i < 4; i++)
            if (rbase + i < N_NODES) Eout[(rbase + i) * 16 + lane] = acc[i];
    }
}

// --------- layer-3 SpMM on batch rows, FULLY fused epilogue ------------------
// out[j] = 0.25*(E0[r] + E1[r] + E2[r] + E3[r]); E3 = spmm acc over E2.
// E1 (=E_a) survives untouched after layer 2, so the two gather kernels are
// deleted: one dispatch writes the whole output, no out-RMW pass.
__global__ void k_spmm_batch(const int* __restrict__ row_ptr,
                             const unsigned long long* __restrict__ edges,
                             const float4* __restrict__ eu4,
                             const float4* __restrict__ ei4s,
                             const float4* __restrict__ E1,
                             const float4* __restrict__ E2,
                             const int* __restrict__ bu, const int* __restrict__ bp,
                             const int* __restrict__ bn,
                             float4* __restrict__ out) {
    int lane = threadIdx.x & 63;
    int j = blockIdx.x * 4 + (threadIdx.x >> 6);
    if (j >= 3 * BATCH) return;
    int r;
    if (j < BATCH)          r = bu[j];
    else if (j < 2 * BATCH) r = N_USERS + bp[j - BATCH];
    else                    r = N_USERS + bn[j - 2 * BATCH];
    float4 acc = spmm_row(row_ptr, edges, E2, E2, r, lane);
    if (lane < 16) {
        const float4* basep = (r < N_USERS) ? eu4 : ei4s;
        float4 e0 = basep[r * 16 + lane];
        float4 e1 = E1[r * 16 + lane];
        float4 e2 = E2[r * 16 + lane];
        float4 o;
        o.x = 0.25f * (e0.x + e1.x + e2.x + acc.x);
        o.y = 0.25f * (e0.y + e1.y + e2.y + acc.y);
        o.z = 0.25f * (e0.z + e1.z + e2.z + acc.z);
        o.w = 0.25f * (e0.w + e1.w + e2.w + acc.w);
        out[j * 16 + lane] = o;
    }
}

extern "C" void kernel_launch(void* const* d_in, const int* in_sizes, int n_in,
                              void* d_out, int out_size, void* d_ws, size_t ws_size,
                              hipStream_t stream) {
    const int*   bu   = (const int*)d_in[0];
    const int*   bp   = (const int*)d_in[1];
    const int*   bn   = (const int*)d_in[2];
    const float* eu   = (const float*)d_in[3];
    const float* ei   = (const float*)d_in[4];
    const int*   row  = (const int*)d_in[5];
    const int*   col  = (const int*)d_in[6];
    const float* vals = (const float*)d_in[7];
    float* out = (float*)d_out;

    char* p = (char*)d_ws;
    auto alloc = [&](size_t nbytes) {
        void* r = (void*)p;
        p += (nbytes + 255) & ~(size_t)255;
        return r;
    };
    float*              E_a     = (float*)alloc((size_t)N_NODES * EMBED * 4);  // 38.4 MB
    float*              E_b     = (float*)alloc((size_t)N_NODES * EMBED * 4);  // 38.4 MB
    unsigned long long* edges   = (unsigned long long*)alloc((size_t)NNZV * 8);// 32.0 MB
    int*                row_ptr = (int*)alloc((N_NODES + 1) * 4);
    int*                bcnt    = (int*)alloc(NBKT * 4);
    int*                bbase   = (int*)alloc(NBKT * 4);
    (void)ws_size; (void)n_in; (void)in_sizes; (void)out_size;

    // staging (NBKT*CAP*8 = 37.5 MB) overlays E_b (38.4 MB): staging is dead
    // after k_partb, before layer-2 spmm writes E_b (same stream => ordered).
    // Footprint = the R0/R6/R8-proven ~109 MB envelope.
    unsigned long long* staging = (unsigned long long*)E_b;

    const float4* eu4  = (const float4*)eu;
    const float4* ei4s = (const float4*)ei - (size_t)N_USERS * 16;  // pre-shifted

    const int nnz = NNZV;
    hipMemsetAsync(bcnt, 0, NBKT * sizeof(int), stream);

    k_parta<<<(nnz + 16383) / 16384, 512, 0, stream>>>(row, col, vals, bcnt, staging, nnz);
    k_bscan<<<1, 512, 0, stream>>>(bcnt, bbase);
    k_partb<<<NBKT, 512, 0, stream>>>(bcnt, bbase, staging, row_ptr, edges);

    // layer 1: E1 = A * E0 (virtual concat input)
    k_spmm4<<<(N_NODES + 15) / 16, 256, 0, stream>>>(row_ptr, edges, eu4, ei4s,
                                                     (float4*)E_a);
    // layer 2: E2 = A * E1 (global node ids -> same base twice, no shift)
    k_spmm4<<<(N_NODES + 15) / 16, 256, 0, stream>>>(row_ptr, edges,
                                                     (const float4*)E_a,
                                                     (const float4*)E_a,
                                                     (float4*)E_b);

    // layer 3 + full epilogue: out = 0.25*(E0+E1+E2+E3)[batch], one dispatch
    k_spmm_batch<<<(3 * BATCH + 3) / 4, 256, 0, stream>>>(
        row_ptr, edges, eu4, ei4s, (const float4*)E_a, (const float4*)E_b,
        bu, bp, bn, (float4*)out);
}